// Round 13
// baseline (564.928 us; speedup 1.0000x reference)
//
#include <hip/hip_runtime.h>
#include <math.h>

// VecPointNet on MI355X, round 19: layerBA 32 pts/block (sequential pgs).
// R18 (knn/stage1 micro-opts) neutral -> reverted to R17 baseline; three flat
// rounds say the cost is layerBA's per-block serial chain with ~2 blocks/CU.
// layerBA v3: 512 blocks x 32 pts (two 16-pt groups processed SEQUENTIALLY
// with the identical per-pg body -> VGPR unchanged, under the 64-reg cliff).
// Both pgs staged at kernel top (pg1's HBM latency hides under pg0 compute),
// bias GEMM once per 32 pts, 512 blocks = exactly 2/CU fully co-resident.
// gsh accumulated per-pg, one atomic set at end (atomic order already
// nondeterministic in passing kernel). All else byte-identical to R17 (495.6).

#define EPSV 1e-12f
#define KCAP 96
#define PSTR 400          // stash point stride (us); 800B = 8 banks mod 32
#define HALF 6400         // 16 * PSTR

typedef unsigned short us;
typedef unsigned long long u64;
typedef __attribute__((ext_vector_type(8))) short short8;
typedef __attribute__((ext_vector_type(4))) float f32x4;

__device__ __forceinline__ us f2bf(float f) {
    unsigned int u = __float_as_uint(f);
    unsigned int r = (u + 0x7FFFu + ((u >> 16) & 1u)) >> 16;
    return (us)r;
}
__device__ __forceinline__ float bf2f(us s) {
    return __uint_as_float(((unsigned int)s) << 16);
}
__device__ __forceinline__ void wsplit(float v, us* __restrict__ hi, us* __restrict__ lo,
                                       size_t o) {
    us h = f2bf(v);
    hi[o] = h;
    lo[o] = f2bf(v - bf2f(h));
}
__device__ __forceinline__ unsigned int fflip(float f) {
    unsigned int u = __float_as_uint(f);
    return (u & 0x80000000u) ? ~u : (u | 0x80000000u);
}

#define MFMA_BF16 __builtin_amdgcn_mfma_f32_16x16x32_bf16
__device__ __forceinline__ void mfma3(f32x4& acc, short8 ah, short8 al, short8 bh, short8 bl) {
    acc = MFMA_BF16(ah, bh, acc, 0, 0, 0);
    acc = MFMA_BF16(ah, bl, acc, 0, 0, 0);
    acc = MFMA_BF16(al, bh, acc, 0, 0, 0);
}

// ---------------------------------------------------------------- KNN (R17: float4 LDS)
__global__ __launch_bounds__(256) void knn_kernel(const float* __restrict__ x,
                                                  int* __restrict__ idx) {
    __shared__ float4 pxyz[2048];
    __shared__ u64 pre[8][64];
    __shared__ u64 buf[8][KCAP];
    __shared__ u64 tauv[8];
    __shared__ int cnt[8];
    int t = threadIdx.x;
    int b = blockIdx.y, q0 = blockIdx.x * 8;
    for (int i = t; i < 2048; i += 256) {
        float vx = x[b * 6144 + i], vy = x[b * 6144 + 2048 + i], vz = x[b * 6144 + 4096 + i];
        float sq = __fadd_rn(__fadd_rn(__fmul_rn(vx, vx), __fmul_rn(vy, vy)),
                             __fmul_rn(vz, vz));
        pxyz[i] = make_float4(vx, vy, vz, sq);
    }
    if (t < 8) cnt[t] = 0;
    __syncthreads();
    int lq = t >> 5, sub = t & 31;
    int q = q0 + lq;
    float4 pq = pxyz[q];
    float qx = pq.x, qy = pq.y, qz = pq.z;
    float sqn = pq.w;

    u64 k0 = ~0ull, k1 = ~0ull;
    unsigned f1 = 0xffffffffu;
    for (int jj = 0; jj < 64; ++jj) {
        int m = sub + jj * 32;
        float4 pm = pxyz[m];
        float dot = __fadd_rn(__fadd_rn(__fmul_rn(qx, pm.x), __fmul_rn(qy, pm.y)),
                              __fmul_rn(qz, pm.z));
        float d2 = __fsub_rn(__fadd_rn(sqn, pm.w), __fmul_rn(2.0f, dot));
        unsigned ff = fflip(d2);
        if (ff < f1) {
            u64 key = (((u64)ff) << 32) | (unsigned)m;
            bool lt0 = key < k0;
            k1 = lt0 ? k0 : key;
            k0 = lt0 ? key : k0;
            f1 = (unsigned)(k1 >> 32);
        }
    }
    pre[lq][2 * sub] = k0;
    pre[lq][2 * sub + 1] = k1;
    __syncthreads();
    {
        int ra = 0, rb = 0;
        for (int j = 0; j < 64; ++j) {
            u64 pj = pre[lq][j];
            ra += (pj < k0);
            rb += (pj < k1);
        }
        if (ra == 15) tauv[lq] = k0;
        if (rb == 15) tauv[lq] = k1;
    }
    __syncthreads();
    u64 tau = tauv[lq];
    unsigned tauhi = (unsigned)(tau >> 32);
    for (int jj = 0; jj < 64; ++jj) {
        int m = sub + jj * 32;
        float4 pm = pxyz[m];
        float dot = __fadd_rn(__fadd_rn(__fmul_rn(qx, pm.x), __fmul_rn(qy, pm.y)),
                              __fmul_rn(qz, pm.z));
        float d2 = __fsub_rn(__fadd_rn(sqn, pm.w), __fmul_rn(2.0f, dot));
        unsigned ff = fflip(d2);
        if (ff <= tauhi) {
            u64 key = (((u64)ff) << 32) | (unsigned)m;
            if (key <= tau) {
                int pos = atomicAdd(&cnt[lq], 1);
                if (pos < KCAP) buf[lq][pos] = key;
            }
        }
    }
    __syncthreads();
    int c = min(cnt[lq], KCAP);
    for (int s = sub; s < c; s += 32) {
        u64 k = buf[lq][s];
        int r = 0;
        for (int j = 0; j < c; ++j) r += (buf[lq][j] < k);
        if (r < 16) idx[(b * 2048 + q) * 16 + r] = (int)(unsigned)(k & 0xffffffffull);
    }
}

// ---------------------------------------------------------------- precompute (unchanged)
__global__ __launch_bounds__(256) void precompute_kernel(
    const float* __restrict__ Win, const float* __restrict__ Wdin,
    const float* __restrict__ Ws, const float* __restrict__ Wds,
    const float* __restrict__ Gs, const float* __restrict__ Gds,
    const float* __restrict__ Wout,
    us* __restrict__ W1h, us* __restrict__ W1l,
    us* __restrict__ W2h, us* __restrict__ W2l,
    float* __restrict__ Wg, us* __restrict__ Woh, us* __restrict__ Wol,
    float* __restrict__ Mbuf, float* __restrict__ Gbuf) {
    __shared__ float row[128];
    int blk = blockIdx.x, t = threadIdx.x;
    if (blk < 512) {
        int l = blk >> 7, i = blk & 127;
        if (t < 128) row[t] = Wds[l * 16384 + i * 128 + t];
        __syncthreads();
        if (t < 128) {
            float acc = 0.f;
            for (int m = 0; m < 128; ++m) acc += row[m] * Ws[l * 16384 + m * 128 + t];
            wsplit(acc, W1h, W1l, (size_t)l * 32768 + (128 + i) * 128 + t);
            wsplit(Ws[l * 16384 + i * 128 + t], W1h, W1l, (size_t)l * 32768 + i * 128 + t);
        }
    } else if (blk < 1024) {
        int l = (blk - 512) >> 7, i = (blk - 512) & 127;
        if (t < 128) row[t] = Gds[l * 16384 + i * 128 + t];
        __syncthreads();
        float acc = 0.f;
        for (int m = 0; m < 128; ++m) acc += row[m] * Gs[l * 32768 + m * 256 + t];
        if (t < 128) {
            wsplit(acc, W2h, W2l, (size_t)l * 32768 + (128 + i) * 128 + t);
            wsplit(Gs[l * 32768 + i * 256 + t], W2h, W2l, (size_t)l * 32768 + i * 128 + t);
        } else {
            Wg[l * 32768 + (128 + i) * 128 + (t - 128)] = acc;
            Wg[l * 32768 + i * 128 + (t - 128)] = Gs[l * 32768 + i * 256 + t];
        }
    } else if (blk == 1024) {
        if (t < 128) {
            float a0 = 0.f, a1 = 0.f, a2 = 0.f;
            for (int m = 0; m < 128; ++m) {
                float w = Wdin[t * 128 + m];
                a0 += w * Win[m * 3];
                a1 += w * Win[m * 3 + 1];
                a2 += w * Win[m * 3 + 2];
            }
            Mbuf[t * 3] = a0; Mbuf[t * 3 + 1] = a1; Mbuf[t * 3 + 2] = a2;
        } else if (t < 137) {
            int qq = t - 128, a = qq / 3, bb = qq - 3 * a;
            float acc = 0.f;
            for (int m = 0; m < 128; ++m) acc += Win[m * 3 + a] * Win[m * 3 + bb];
            Gbuf[qq] = acc;
        }
    } else {
        int l = blk - 1025;
        for (int i = t; i < 16384; i += 256) {
            int r = i >> 7, j = i & 127;
            wsplit(Wout[r * 512 + l * 128 + j], Woh, Wol, (size_t)l * 16384 + r * 128 + j);
        }
    }
}

// ---------------------------------------------------------------- stage 1 (R17-exact)
__global__ __launch_bounds__(256) void stage1_kernel(
    const float* __restrict__ x, const int* __restrict__ idx,
    const float* __restrict__ Win, const float* __restrict__ Mbuf,
    const float* __restrict__ Gbuf, us* __restrict__ hhi, us* __restrict__ hlo) {
    __shared__ float Yb[2][16][10];
    __shared__ float Pb[2][16][6];
    __shared__ float SYb[2][9];
    int t = threadIdx.x;
    int blk = blockIdx.x;
    int b = blk >> 10, n0 = (blk & 1023) * 2;
    if (t < 32) {
        int pt = t >> 4, k = t & 15;
        int n = n0 + pt, gpt = b * 2048 + n;
        float pxv = x[b * 6144 + n], pyv = x[b * 6144 + 2048 + n], pzv = x[b * 6144 + 4096 + n];
        float pn = sqrtf(pxv * pxv + pyv * pyv + pzv * pzv);
        float inv = 1.f / fmaxf(pn, EPSV);
        float dx = pxv * inv, dy = pyv * inv, dz = pzv * inv;
        int m = idx[gpt * 16 + k];
        float qx = x[b * 6144 + m], qy = x[b * 6144 + 2048 + m], qz = x[b * 6144 + 4096 + m];
        float Y[9];
        Y[0] = dy * qz - dz * qy; Y[1] = dz * qx - dx * qz; Y[2] = dx * qy - dy * qx;
        Y[3] = qx - pxv; Y[4] = qy - pyv; Y[5] = qz - pzv;
        Y[6] = pxv; Y[7] = pyv; Y[8] = pzv;
        float P[6];
        P[0] = Y[0] * Y[0] + Y[1] * Y[1] + Y[2] * Y[2];
        P[1] = Y[0] * Y[3] + Y[1] * Y[4] + Y[2] * Y[5];
        P[2] = Y[0] * Y[6] + Y[1] * Y[7] + Y[2] * Y[8];
        P[3] = Y[3] * Y[3] + Y[4] * Y[4] + Y[5] * Y[5];
        P[4] = Y[3] * Y[6] + Y[4] * Y[7] + Y[5] * Y[8];
        P[5] = Y[6] * Y[6] + Y[7] * Y[7] + Y[8] * Y[8];
        float nv2 = Gbuf[0] * P[0] + Gbuf[4] * P[3] + Gbuf[8] * P[5] +
                    (Gbuf[1] + Gbuf[3]) * P[1] + (Gbuf[2] + Gbuf[6]) * P[2] +
                    (Gbuf[5] + Gbuf[7]) * P[4];
        float s = 1.f / fmaxf(sqrtf(nv2), EPSV);
#pragma unroll
        for (int j = 0; j < 9; ++j) Yb[pt][k][j] = Y[j];
        Yb[pt][k][9] = s;
#pragma unroll
        for (int j = 0; j < 6; ++j) Pb[pt][k][j] = P[j];
    }
    __syncthreads();
    if (t < 18) {
        int pt = t / 9, j = t - 9 * pt;
        float acc = 0.f;
#pragma unroll
        for (int k = 0; k < 16; ++k) acc += Yb[pt][k][j] * Yb[pt][k][9];
        SYb[pt][j] = acc;
    }
    __syncthreads();
    int pt = t >> 7, h = t & 127;
    int n = n0 + pt;
    float w0 = Win[h * 3], w1 = Win[h * 3 + 1], w2 = Win[h * 3 + 2];
    float m0 = Mbuf[h * 3], m1 = Mbuf[h * 3 + 1], m2 = Mbuf[h * 3 + 2];
    float cA0 = w0 * m0, cA3 = w1 * m1, cA5 = w2 * m2;
    float cA1 = w0 * m1 + w1 * m0, cA2 = w0 * m2 + w2 * m0, cA4 = w1 * m2 + w2 * m1;
    float cR0 = m0 * m0, cR3 = m1 * m1, cR5 = m2 * m2;
    float cR1 = 2.f * m0 * m1, cR2 = 2.f * m0 * m2, cR4 = 2.f * m1 * m2;
    float wY[9] = {0.f, 0.f, 0.f, 0.f, 0.f, 0.f, 0.f, 0.f, 0.f};
    for (int k = 0; k < 16; ++k) {
        const float* Y = Yb[pt][k];
        const float* P = Pb[pt][k];
        float s = Y[9];
        float a = cA0 * P[0] + cA1 * P[1] + cA2 * P[2] + cA3 * P[3] + cA4 * P[4] + cA5 * P[5];
        float r2 = cR0 * P[0] + cR1 * P[1] + cR2 * P[2] + cR3 * P[3] + cR4 * P[4] + cR5 * P[5];
        float an = fminf(a, 0.f);
        float wc = -an * s * __builtin_amdgcn_rcpf(fmaxf(r2, 1e-30f));
#pragma unroll
        for (int j = 0; j < 9; ++j) wY[j] += wc * Y[j];
    }
#pragma unroll
    for (int c = 0; c < 3; ++c) {
        float base = w0 * SYb[pt][c] + w1 * SYb[pt][3 + c] + w2 * SYb[pt][6 + c];
        float corr = m0 * wY[c] + m1 * wY[3 + c] + m2 * wY[6 + c];
        wsplit((base + corr) * (1.f / 16.f), hhi, hlo,
               (size_t)(b * 2048 + n) * 384 + c * 128 + h);
    }
}

// ---------------------------------------------------------------- GEMM helpers
__device__ __forceinline__ void gemm16(
    const us* __restrict__ wvh, const us* __restrict__ wvl,
    const us* __restrict__ wkh, const us* __restrict__ wkl,
    const us* __restrict__ sh, const us* __restrict__ sl,
    int r15, int quad, f32x4 (&av)[3], f32x4 (&ak)[3]) {
#pragma unroll
    for (int j = 0; j < 3; ++j) { av[j] = (f32x4){0.f, 0.f, 0.f, 0.f}; ak[j] = av[j]; }
#pragma unroll
    for (int kc4 = 0; kc4 < 4; ++kc4) {
        int ko = kc4 * 32 + quad * 8;
        short8 avh = *(const short8*)(wvh + ko);
        short8 avl = *(const short8*)(wvl + ko);
        short8 akh = *(const short8*)(wkh + ko);
        short8 akl = *(const short8*)(wkl + ko);
        const us* bp = sh + r15 * PSTR + ko;
        const us* blp = sl + r15 * PSTR + ko;
        short8 bh0 = *(const short8*)(bp);
        short8 bh1 = *(const short8*)(bp + 128);
        short8 bh2 = *(const short8*)(bp + 256);
        short8 bl0 = *(const short8*)(blp);
        short8 bl1 = *(const short8*)(blp + 128);
        short8 bl2 = *(const short8*)(blp + 256);
        mfma3(av[0], avh, avl, bh0, bl0);
        mfma3(av[1], avh, avl, bh1, bl1);
        mfma3(av[2], avh, avl, bh2, bl2);
        mfma3(ak[0], akh, akl, bh0, bl0);
        mfma3(ak[1], akh, akl, bh1, bl1);
        mfma3(ak[2], akh, akl, bh2, bl2);
    }
}

__device__ __forceinline__ void wout16(
    const us* __restrict__ woh, const us* __restrict__ wol,
    const us* __restrict__ sh, const us* __restrict__ sl,
    int r15, int quad, f32x4 (&wa)[3]) {
#pragma unroll
    for (int kc4 = 0; kc4 < 4; ++kc4) {
        int ko = kc4 * 32 + quad * 8;
        short8 ah = *(const short8*)(woh + ko);
        short8 al = *(const short8*)(wol + ko);
#pragma unroll
        for (int nt = 0; nt < 3; ++nt) {
            short8 bh = *(const short8*)(sh + r15 * PSTR + nt * 128 + ko);
            short8 bl = *(const short8*)(sl + r15 * PSTR + nt * 128 + ko);
            mfma3(wa[nt], ah, al, bh, bl);
        }
    }
}

// VN activation epilogue, rcp form (no sqrt/div)
__device__ __forceinline__ void vnact(float s, float vx, float vy, float vz,
                                      float kx, float ky, float kz,
                                      float& o0, float& o1, float& o2) {
    float kk = kx * kx + ky * ky + kz * kz;
    float tt = vx * kx + vy * ky + vz * kz;
    float f = fmaxf(-tt, 0.f) * s * __builtin_amdgcn_rcpf(fmaxf(kk, 1e-30f));
    o0 = s * vx + f * kx;
    o1 = s * vy + f * ky;
    o2 = s * vz + f * kz;
}

// single-barrier reduce (bit-identical to old t<16 path)
__device__ __forceinline__ float rsum8(const float (*colsum)[16], int r15) {
    float c = 0.f;
#pragma unroll
    for (int w = 0; w < 8; ++w) c += colsum[w][r15];
    return 1.f / fmaxf(sqrtf(c), EPSV);
}

// ---------------------------------------------------------------- layer A0 (unchanged)
__global__ __launch_bounds__(512, 6) void layerA0_kernel(
    const us* __restrict__ Xhi, const us* __restrict__ Xlo,
    const us* __restrict__ Whi, const us* __restrict__ Wlo,
    us* __restrict__ Hhi, us* __restrict__ Hlo, float* __restrict__ g) {
    __shared__ __align__(16) us stash[2 * HALF];
    __shared__ float colsum[8][16];
    __shared__ float gsh[384];
    us* sh = stash;
    us* sl = stash + HALF;
    int t = threadIdx.x, blk = blockIdx.x;
    int b = blk >> 7, n0 = (blk & 127) * 16;
    size_t pbase = (size_t)(b * 2048 + n0);
    int lane = t & 63, wv = t >> 6;
    int r15 = lane & 15, quad = lane >> 4;
    int rowb = 16 * wv + quad * 4;

    for (int i = t; i < 768; i += 512) {
        int p = i / 48, rem = i - p * 48;
        int c = rem >> 4, k0 = (rem & 15) << 3;
        int lo_ = p * PSTR + c * 128 + k0;
        size_t go = (pbase + p) * 384 + c * 128 + k0;
        *(uint4*)(sh + lo_) = *(const uint4*)(Xhi + go);
        *(uint4*)(sl + lo_) = *(const uint4*)(Xlo + go);
    }
    __syncthreads();

    f32x4 av[3], ak[3];
    gemm16(Whi + (16 * wv + r15) * 128, Wlo + (16 * wv + r15) * 128,
           Whi + (128 + 16 * wv + r15) * 128, Wlo + (128 + 16 * wv + r15) * 128,
           sh, sl, r15, quad, av, ak);

    float S = 0.f;
#pragma unroll
    for (int nt = 0; nt < 3; ++nt)
#pragma unroll
        for (int reg = 0; reg < 4; ++reg) S += av[nt][reg] * av[nt][reg];
    S += __shfl_xor(S, 16, 64);
    S += __shfl_xor(S, 32, 64);
    if (quad == 0) colsum[wv][r15] = S;
    __syncthreads();
    float s = rsum8(colsum, r15);
#pragma unroll
    for (int reg = 0; reg < 4; ++reg) {
        int row = rowb + reg;
        float o0, o1, o2;
        vnact(s, av[0][reg], av[1][reg], av[2][reg],
              ak[0][reg], ak[1][reg], ak[2][reg], o0, o1, o2);
        int sb = r15 * PSTR + row;
        us h0 = f2bf(o0); sh[sb] = h0;           sl[sb] = f2bf(o0 - bf2f(h0));
        us h1 = f2bf(o1); sh[sb + 128] = h1;     sl[sb + 128] = f2bf(o1 - bf2f(h1));
        us h2 = f2bf(o2); sh[sb + 256] = h2;     sl[sb + 256] = f2bf(o2 - bf2f(h2));
        float g0 = o0, g1 = o1, g2 = o2;
#pragma unroll
        for (int m = 1; m < 16; m <<= 1) {
            g0 += __shfl_xor(g0, m, 64);
            g1 += __shfl_xor(g1, m, 64);
            g2 += __shfl_xor(g2, m, 64);
        }
        if (r15 == 0) {
            gsh[row] = g0;
            gsh[128 + row] = g1;
            gsh[256 + row] = g2;
        }
    }
    __syncthreads();
    for (int i = t; i < 768; i += 512) {
        int p = i / 48, rem = i - p * 48;
        int c = rem >> 4, k0 = (rem & 15) << 3;
        int lo_ = p * PSTR + c * 128 + k0;
        size_t go = (pbase + p) * 384 + c * 128 + k0;
        *(uint4*)(Hhi + go) = *(const uint4*)(sh + lo_);
        *(uint4*)(Hlo + go) = *(const uint4*)(sl + lo_);
    }
    if (t < 384) atomicAdd(&g[b * 384 + t], gsh[t]);
}

// ---------------------------------------------------------------- layer BA (v3: 32 pts)
template <int FIRST>
__global__ __launch_bounds__(512, 4) void layerBA_kernel(
    const us* __restrict__ Xhi, const us* __restrict__ Xlo,
    const float* __restrict__ gin, const float* __restrict__ Wgl,
    const us* __restrict__ W2h, const us* __restrict__ W2l,
    const us* __restrict__ Woh, const us* __restrict__ Wol,
    const us* __restrict__ W1h, const us* __restrict__ W1l,
    us* __restrict__ Hhi, us* __restrict__ Hlo, float* __restrict__ gout,
    float* __restrict__ accb) {
    __shared__ __align__(16) us stash[2][2 * HALF];   // [pg][hi | lo]
    __shared__ float gl[384];
    __shared__ float biasl[768];
    __shared__ float colsum[8][16];
    __shared__ float gsh[2][384];
    int t = threadIdx.x, blk = blockIdx.x;
    int b = blk >> 6, n0 = (blk & 63) * 32;
    size_t pbase = (size_t)(b * 2048 + n0);
    int lane = t & 63, wv = t >> 6;
    int r15 = lane & 15, quad = lane >> 4;
    int rowb = 16 * wv + quad * 4;

    // stage BOTH point-groups up front: pg1's HBM latency hides under pg0 compute
    for (int i = t; i < 1536; i += 512) {
        int p = i / 48, rem = i - p * 48;      // p in 0..31
        int pg = p >> 4, pl = p & 15;
        int c = rem >> 4, k0 = (rem & 15) << 3;
        int lo_ = pl * PSTR + c * 128 + k0;
        size_t go = (pbase + p) * 384 + c * 128 + k0;
        *(uint4*)(&stash[pg][lo_]) = *(const uint4*)(Xhi + go);
        *(uint4*)(&stash[pg][HALF + lo_]) = *(const uint4*)(Xlo + go);
    }
    if (t < 384) gl[t] = gin[b * 384 + t] * (1.f / 2048.f);
    __syncthreads();   // gl + stash visible

    // bias once per 32 points (overlaps pg0's first GEMM in the pipeline)
    if (t < 256) {
        float accv[3] = {0.f, 0.f, 0.f};
        const float4* wr = (const float4*)&Wgl[t * 128];
        for (int jj = 0; jj < 32; ++jj) {
            float4 w4 = wr[jj];
#pragma unroll
            for (int c = 0; c < 3; ++c) {
                float4 gq = *(const float4*)&gl[c * 128 + 4 * jj];
                accv[c] += w4.x * gq.x + w4.y * gq.y + w4.z * gq.z + w4.w * gq.w;
            }
        }
#pragma unroll
        for (int c = 0; c < 3; ++c) biasl[c * 256 + t] = accv[c];
    }

#pragma unroll 1
    for (int pg = 0; pg < 2; ++pg) {
        us* sh = &stash[pg][0];
        us* sl = &stash[pg][HALF];
        size_t pgbase = pbase + pg * 16;

        // B GEMM (LDS reads)
        f32x4 av[3], ak[3];
        gemm16(W2h + (16 * wv + r15) * 128, W2l + (16 * wv + r15) * 128,
               W2h + (128 + 16 * wv + r15) * 128, W2l + (128 + 16 * wv + r15) * 128,
               sh, sl, r15, quad, av, ak);
        __syncthreads();   // biasl visible (pg0) / colsum free (pg1); stash B-reads done

        float S = 0.f;
#pragma unroll
        for (int reg = 0; reg < 4; ++reg) {
            int row = rowb + reg;
#pragma unroll
            for (int c = 0; c < 3; ++c) {
                float v = av[c][reg] + biasl[c * 256 + row];
                S += v * v;
            }
        }
        S += __shfl_xor(S, 16, 64);
        S += __shfl_xor(S, 32, 64);
        if (quad == 0) colsum[wv][r15] = S;
        __syncthreads();
        float s = rsum8(colsum, r15);
#pragma unroll
        for (int reg = 0; reg < 4; ++reg) {
            int row = rowb + reg;
            float o0, o1, o2;
            vnact(s, av[0][reg] + biasl[row], av[1][reg] + biasl[256 + row],
                  av[2][reg] + biasl[512 + row],
                  ak[0][reg] + biasl[128 + row], ak[1][reg] + biasl[384 + row],
                  ak[2][reg] + biasl[640 + row], o0, o1, o2);
            int sb = r15 * PSTR + row;
            us h0 = f2bf(o0); sh[sb] = h0;           sl[sb] = f2bf(o0 - bf2f(h0));
            us h1 = f2bf(o1); sh[sb + 128] = h1;     sl[sb + 128] = f2bf(o1 - bf2f(h1));
            us h2 = f2bf(o2); sh[sb + 256] = h2;     sl[sb + 256] = f2bf(o2 - bf2f(h2));
        }
        __syncthreads();   // H_feat visible

        // wout(l) + A(l+1), both read stash
        f32x4 wa[3];
#pragma unroll
        for (int j = 0; j < 3; ++j) wa[j] = (f32x4){0.f, 0.f, 0.f, 0.f};
        wout16(Woh + (16 * wv + r15) * 128, Wol + (16 * wv + r15) * 128,
               sh, sl, r15, quad, wa);
        f32x4 av2[3], ak2[3];
        gemm16(W1h + (16 * wv + r15) * 128, W1l + (16 * wv + r15) * 128,
               W1h + (128 + 16 * wv + r15) * 128, W1l + (128 + 16 * wv + r15) * 128,
               sh, sl, r15, quad, av2, ak2);

        float S2 = 0.f;
#pragma unroll
        for (int nt = 0; nt < 3; ++nt)
#pragma unroll
            for (int reg = 0; reg < 4; ++reg) S2 += av2[nt][reg] * av2[nt][reg];
        S2 += __shfl_xor(S2, 16, 64);
        S2 += __shfl_xor(S2, 32, 64);
        if (quad == 0) colsum[wv][r15] = S2;
        __syncthreads();   // colsum visible AND all stash wout/A reads done
        float s2 = rsum8(colsum, r15);
#pragma unroll
        for (int reg = 0; reg < 4; ++reg) {
            int row = rowb + reg;
            float o0, o1, o2;
            vnact(s2, av2[0][reg], av2[1][reg], av2[2][reg],
                  ak2[0][reg], ak2[1][reg], ak2[2][reg], o0, o1, o2);
            int sb = r15 * PSTR + row;
            us h0 = f2bf(o0); sh[sb] = h0;           sl[sb] = f2bf(o0 - bf2f(h0));
            us h1 = f2bf(o1); sh[sb + 128] = h1;     sl[sb + 128] = f2bf(o1 - bf2f(h1));
            us h2 = f2bf(o2); sh[sb + 256] = h2;     sl[sb + 256] = f2bf(o2 - bf2f(h2));
            float g0 = o0, g1 = o1, g2 = o2;
#pragma unroll
            for (int m = 1; m < 16; m <<= 1) {
                g0 += __shfl_xor(g0, m, 64);
                g1 += __shfl_xor(g1, m, 64);
                g2 += __shfl_xor(g2, m, 64);
            }
            if (r15 == 0) {
                gsh[pg][row] = g0;
                gsh[pg][128 + row] = g1;
                gsh[pg][256 + row] = g2;
            }
        }
        __syncthreads();   // H_A visible
        for (int i = t; i < 768; i += 512) {
            int p = i / 48, rem = i - p * 48;
            int c = rem >> 4, k0 = (rem & 15) << 3;
            int lo_ = p * PSTR + c * 128 + k0;
            size_t go = (pgbase + p) * 384 + c * 128 + k0;
            *(uint4*)(Hhi + go) = *(const uint4*)(&stash[pg][lo_]);
            *(uint4*)(Hlo + go) = *(const uint4*)(&stash[pg][HALF + lo_]);
        }
        __syncthreads();   // dump reads done; this pg's stash reusable
        float* accf = (float*)&stash[pg][0];
#pragma unroll
        for (int nt = 0; nt < 3; ++nt)
#pragma unroll
            for (int reg = 0; reg < 4; ++reg)
                accf[r15 * PSTR + nt * 128 + rowb + reg] = wa[nt][reg];
        __syncthreads();
        // tight RMW at tail per pg (R14 lesson)
        for (int i = t; i < 1536; i += 512) {
            int p = i / 96, rem = i - p * 96;
            int c = rem >> 5, k4 = (rem & 31) << 2;
            float4 vv = *(const float4*)&accf[p * PSTR + c * 128 + k4];
            size_t go = (pgbase + p) * 384 + c * 128 + k4;
            if (FIRST) {
                *(float4*)&accb[go] = vv;
            } else {
                float4 old = *(const float4*)&accb[go];
                old.x += vv.x; old.y += vv.y; old.z += vv.z; old.w += vv.w;
                *(float4*)&accb[go] = old;
            }
        }
        __syncthreads();   // accf reads done before next pg reuses colsum etc.
    }
    // deferred g atomics: one add of both pg partials
    if (t < 384) atomicAdd(&gout[b * 384 + t], gsh[0][t] + gsh[1][t]);
}

// ---------------------------------------------------------------- layer B3 + out (unchanged)
__global__ __launch_bounds__(512, 6) void layerB3_kernel(
    const us* __restrict__ Xhi, const us* __restrict__ Xlo,
    const float* __restrict__ gin, const float* __restrict__ Wgl,
    const us* __restrict__ W2h, const us* __restrict__ W2l,
    const us* __restrict__ Woh, const us* __restrict__ Wol,
    const float* __restrict__ accb,
    float* __restrict__ out1, float* __restrict__ out0) {
    __shared__ __align__(16) us stash[2 * HALF];
    __shared__ float gl[384];
    __shared__ float biasl[768];
    __shared__ float colsum[8][16];
    us* sh = stash;
    us* sl = stash + HALF;
    int t = threadIdx.x, blk = blockIdx.x;
    int b = blk >> 7, n0 = (blk & 127) * 16;
    size_t pbase = (size_t)(b * 2048 + n0);
    int lane = t & 63, wv = t >> 6;
    int r15 = lane & 15, quad = lane >> 4;
    int rowb = 16 * wv + quad * 4;

    for (int i = t; i < 768; i += 512) {
        int p = i / 48, rem = i - p * 48;
        int c = rem >> 4, k0 = (rem & 15) << 3;
        int lo_ = p * PSTR + c * 128 + k0;
        size_t go = (pbase + p) * 384 + c * 128 + k0;
        *(uint4*)(sh + lo_) = *(const uint4*)(Xhi + go);
        *(uint4*)(sl + lo_) = *(const uint4*)(Xlo + go);
    }
    if (t < 384) gl[t] = gin[b * 384 + t] * (1.f / 2048.f);
    __syncthreads();

    f32x4 av[3], ak[3];
    gemm16(W2h + (16 * wv + r15) * 128, W2l + (16 * wv + r15) * 128,
           W2h + (128 + 16 * wv + r15) * 128, W2l + (128 + 16 * wv + r15) * 128,
           sh, sl, r15, quad, av, ak);
    if (t < 256) {
        float accv[3] = {0.f, 0.f, 0.f};
        const float4* wr = (const float4*)&Wgl[t * 128];
        for (int jj = 0; jj < 32; ++jj) {
            float4 w4 = wr[jj];
#pragma unroll
            for (int c = 0; c < 3; ++c) {
                float4 gq = *(const float4*)&gl[c * 128 + 4 * jj];
                accv[c] += w4.x * gq.x + w4.y * gq.y + w4.z * gq.z + w4.w * gq.w;
            }
        }
#pragma unroll
        for (int c = 0; c < 3; ++c) biasl[c * 256 + t] = accv[c];
    }
    __syncthreads();

    float S = 0.f;
#pragma unroll
    for (int reg = 0; reg < 4; ++reg) {
        int row = rowb + reg;
#pragma unroll
        for (int c = 0; c < 3; ++c) {
            float v = av[c][reg] + biasl[c * 256 + row];
            S += v * v;
        }
    }
    S += __shfl_xor(S, 16, 64);
    S += __shfl_xor(S, 32, 64);
    if (quad == 0) colsum[wv][r15] = S;
    __syncthreads();
    float s = rsum8(colsum, r15);
#pragma unroll
    for (int reg = 0; reg < 4; ++reg) {
        int row = rowb + reg;
        float o0, o1, o2;
        vnact(s, av[0][reg] + biasl[row], av[1][reg] + biasl[256 + row],
              av[2][reg] + biasl[512 + row],
              ak[0][reg] + biasl[128 + row], ak[1][reg] + biasl[384 + row],
              ak[2][reg] + biasl[640 + row], o0, o1, o2);
        int sb = r15 * PSTR + row;
        us h0 = f2bf(o0); sh[sb] = h0;           sl[sb] = f2bf(o0 - bf2f(h0));
        us h1 = f2bf(o1); sh[sb + 128] = h1;     sl[sb + 128] = f2bf(o1 - bf2f(h1));
        us h2 = f2bf(o2); sh[sb + 256] = h2;     sl[sb + 256] = f2bf(o2 - bf2f(h2));
    }
    __syncthreads();

    f32x4 wa[3];
#pragma unroll
    for (int j = 0; j < 3; ++j) wa[j] = (f32x4){0.f, 0.f, 0.f, 0.f};
    wout16(Woh + (16 * wv + r15) * 128, Wol + (16 * wv + r15) * 128,
           sh, sl, r15, quad, wa);
    __syncthreads();
    float* accf = (float*)stash;
#pragma unroll
    for (int nt = 0; nt < 3; ++nt)
#pragma unroll
        for (int reg = 0; reg < 4; ++reg)
            accf[r15 * PSTR + nt * 128 + rowb + reg] = wa[nt][reg];
    __syncthreads();
    for (int i = t; i < 1536; i += 512) {
        int p = i / 96, rem = i - p * 96;
        int c = rem >> 5, k4 = (rem & 31) << 2;
        size_t go = (pbase + p) * 384 + c * 128 + k4;
        float4 old = *(const float4*)&accb[go];
        float4* pl = (float4*)&accf[p * PSTR + c * 128 + k4];
        float4 vv = *pl;
        vv.x += old.x; vv.y += old.y; vv.z += old.z; vv.w += old.w;
        *pl = vv;
    }
    __syncthreads();
    for (int i = t; i < 6144; i += 512) {
        int j = i >> 4, nl = i & 15;
        float v = accf[nl * PSTR + j];
        out1[((size_t)b * 384 + (j & 127) * 3 + (j >> 7)) * 2048 + n0 + nl] = v;
    }
    if (t < 384) {
        float ssum = 0.f;
#pragma unroll
        for (int nl = 0; nl < 16; ++nl) ssum += accf[nl * PSTR + t];
        atomicAdd(&out0[b * 384 + (t & 127) * 3 + (t >> 7)], ssum * (1.f / 2048.f));
    }
}

// ---------------------------------------------------------------- launch
extern "C" void kernel_launch(void* const* d_in, const int* in_sizes, int n_in,
                              void* d_out, int out_size, void* d_ws, size_t ws_size,
                              hipStream_t stream) {
    const float* x    = (const float*)d_in[0];
    const float* Win  = (const float*)d_in[1];
    const float* Wdin = (const float*)d_in[2];
    const float* Ws   = (const float*)d_in[3];
    const float* Wds  = (const float*)d_in[4];
    const float* Gs   = (const float*)d_in[5];
    const float* Gds  = (const float*)d_in[6];
    const float* Wout = (const float*)d_in[7];

    float* out0 = (float*)d_out;   // (B,CD,3) = 3072
    float* out1 = out0 + 3072;     // (B,CD,3,N)

    char* ws = (char*)d_ws;
    int* idx = (int*)ws;                            // 1 MB
    us* hAhi = (us*)(ws + (1 << 20));               // 6291456 bf16 each
    us* hAlo = hAhi + 6291456;
    us* hBhi = hAlo + 6291456;
    us* hBlo = hBhi + 6291456;
    float* acc = (float*)(hBlo + 6291456);          // 6291456 f32
    float* g4 = acc + 6291456;                      // 4 x 3072
    us* W1h = (us*)(g4 + 12288);                    // 131072 each
    us* W1l = W1h + 131072;
    us* W2h = W1l + 131072;
    us* W2l = W2h + 131072;
    us* Woh = W2l + 131072;                         // 65536 each
    us* Wol = Woh + 65536;
    float* Wg = (float*)(Wol + 65536);              // 131072 f32
    float* Mbuf = Wg + 131072;                      // 384
    float* Gbuf = Mbuf + 384;                       // 16

    hipMemsetAsync(out0, 0, (size_t)3072 * 4, stream);
    hipMemsetAsync(g4, 0, (size_t)12288 * 4, stream);

    knn_kernel<<<dim3(256, 8), 256, 0, stream>>>(x, idx);
    precompute_kernel<<<1029, 256, 0, stream>>>(Win, Wdin, Ws, Wds, Gs, Gds, Wout,
                                                W1h, W1l, W2h, W2l, Wg, Woh, Wol,
                                                Mbuf, Gbuf);
    stage1_kernel<<<8192, 256, 0, stream>>>(x, idx, Win, Mbuf, Gbuf, hAhi, hAlo);

    // A(0): hA -> hB, g4[0]
    layerA0_kernel<<<1024, 512, 0, stream>>>(hAhi, hAlo, W1h, W1l, hBhi, hBlo, g4);
    // B(0)+wout(0)+A(1): hB -> hA, g4[1], acc (first write)   [512 blocks, 32 pts]
    layerBA_kernel<1><<<512, 512, 0, stream>>>(
        hBhi, hBlo, g4, Wg, W2h, W2l, Woh, Wol,
        W1h + 32768, W1l + 32768, hAhi, hAlo, g4 + 3072, acc);
    // B(1)+wout(1)+A(2): hA -> hB, g4[2], acc +=
    layerBA_kernel<0><<<512, 512, 0, stream>>>(
        hAhi, hAlo, g4 + 3072, Wg + 32768, W2h + 32768, W2l + 32768,
        Woh + 16384, Wol + 16384, W1h + 65536, W1l + 65536,
        hBhi, hBlo, g4 + 6144, acc);
    // B(2)+wout(2)+A(3): hB -> hA, g4[3], acc +=
    layerBA_kernel<0><<<512, 512, 0, stream>>>(
        hBhi, hBlo, g4 + 6144, Wg + 65536, W2h + 65536, W2l + 65536,
        Woh + 32768, Wol + 32768, W1h + 98304, W1l + 98304,
        hAhi, hAlo, g4 + 9216, acc);
    // B(3)+wout(3) + acc readback -> out1/out0
    layerB3_kernel<<<1024, 512, 0, stream>>>(
        hAhi, hAlo, g4 + 9216, Wg + 98304, W2h + 98304, W2l + 98304,
        Woh + 49152, Wol + 49152, acc, out1, out0);
}

// Round 14
// 493.241 us; speedup vs baseline: 1.1453x; 1.1453x over previous
//
#include <hip/hip_runtime.h>
#include <math.h>

// VecPointNet on MI355X, round 20: REVERT to R17 (best verified: 495.6us).
// R19 (32 pts/block) regressed 495.6->564.9: FETCH 28->157MB, WRITE 51->180MB.
// Confirmed lesson (2nd time): stretching producer->consumer reuse windows
// through L2 (longer-lived blocks, split RMW) multiplies HBM traffic 3-4x and
// loses more than latency-hiding gains. Ledger of structural attempts: coop
// fusion x2 = deterministic numerics failure; stage1A merge = late harness
// check failure; acc prefetch = -48us; 32pts/block = -69us; rsum8/knn-f4/
// stage1-pack = neutral. No pipe saturated (Mfma 12/VALU 19/HBM 13) but this
// decomposition's empirical floor is ~495us: remaining cost is inter-phase
// latency removable only via cross-block fusion, closed by measurement.

#define EPSV 1e-12f
#define KCAP 96
#define PSTR 400          // stash point stride (us); 800B = 8 banks mod 32
#define HALF 6400         // 16 * PSTR

typedef unsigned short us;
typedef unsigned long long u64;
typedef __attribute__((ext_vector_type(8))) short short8;
typedef __attribute__((ext_vector_type(4))) float f32x4;

__device__ __forceinline__ us f2bf(float f) {
    unsigned int u = __float_as_uint(f);
    unsigned int r = (u + 0x7FFFu + ((u >> 16) & 1u)) >> 16;
    return (us)r;
}
__device__ __forceinline__ float bf2f(us s) {
    return __uint_as_float(((unsigned int)s) << 16);
}
__device__ __forceinline__ void wsplit(float v, us* __restrict__ hi, us* __restrict__ lo,
                                       size_t o) {
    us h = f2bf(v);
    hi[o] = h;
    lo[o] = f2bf(v - bf2f(h));
}
__device__ __forceinline__ unsigned int fflip(float f) {
    unsigned int u = __float_as_uint(f);
    return (u & 0x80000000u) ? ~u : (u | 0x80000000u);
}

#define MFMA_BF16 __builtin_amdgcn_mfma_f32_16x16x32_bf16
__device__ __forceinline__ void mfma3(f32x4& acc, short8 ah, short8 al, short8 bh, short8 bl) {
    acc = MFMA_BF16(ah, bh, acc, 0, 0, 0);
    acc = MFMA_BF16(ah, bl, acc, 0, 0, 0);
    acc = MFMA_BF16(al, bh, acc, 0, 0, 0);
}

// ---------------------------------------------------------------- KNN (float4 LDS)
__global__ __launch_bounds__(256) void knn_kernel(const float* __restrict__ x,
                                                  int* __restrict__ idx) {
    __shared__ float4 pxyz[2048];
    __shared__ u64 pre[8][64];
    __shared__ u64 buf[8][KCAP];
    __shared__ u64 tauv[8];
    __shared__ int cnt[8];
    int t = threadIdx.x;
    int b = blockIdx.y, q0 = blockIdx.x * 8;
    for (int i = t; i < 2048; i += 256) {
        float vx = x[b * 6144 + i], vy = x[b * 6144 + 2048 + i], vz = x[b * 6144 + 4096 + i];
        float sq = __fadd_rn(__fadd_rn(__fmul_rn(vx, vx), __fmul_rn(vy, vy)),
                             __fmul_rn(vz, vz));
        pxyz[i] = make_float4(vx, vy, vz, sq);
    }
    if (t < 8) cnt[t] = 0;
    __syncthreads();
    int lq = t >> 5, sub = t & 31;
    int q = q0 + lq;
    float4 pq = pxyz[q];
    float qx = pq.x, qy = pq.y, qz = pq.z;
    float sqn = pq.w;

    u64 k0 = ~0ull, k1 = ~0ull;
    unsigned f1 = 0xffffffffu;
    for (int jj = 0; jj < 64; ++jj) {
        int m = sub + jj * 32;
        float4 pm = pxyz[m];
        float dot = __fadd_rn(__fadd_rn(__fmul_rn(qx, pm.x), __fmul_rn(qy, pm.y)),
                              __fmul_rn(qz, pm.z));
        float d2 = __fsub_rn(__fadd_rn(sqn, pm.w), __fmul_rn(2.0f, dot));
        unsigned ff = fflip(d2);
        if (ff < f1) {
            u64 key = (((u64)ff) << 32) | (unsigned)m;
            bool lt0 = key < k0;
            k1 = lt0 ? k0 : key;
            k0 = lt0 ? key : k0;
            f1 = (unsigned)(k1 >> 32);
        }
    }
    pre[lq][2 * sub] = k0;
    pre[lq][2 * sub + 1] = k1;
    __syncthreads();
    {
        int ra = 0, rb = 0;
        for (int j = 0; j < 64; ++j) {
            u64 pj = pre[lq][j];
            ra += (pj < k0);
            rb += (pj < k1);
        }
        if (ra == 15) tauv[lq] = k0;
        if (rb == 15) tauv[lq] = k1;
    }
    __syncthreads();
    u64 tau = tauv[lq];
    unsigned tauhi = (unsigned)(tau >> 32);
    for (int jj = 0; jj < 64; ++jj) {
        int m = sub + jj * 32;
        float4 pm = pxyz[m];
        float dot = __fadd_rn(__fadd_rn(__fmul_rn(qx, pm.x), __fmul_rn(qy, pm.y)),
                              __fmul_rn(qz, pm.z));
        float d2 = __fsub_rn(__fadd_rn(sqn, pm.w), __fmul_rn(2.0f, dot));
        unsigned ff = fflip(d2);
        if (ff <= tauhi) {
            u64 key = (((u64)ff) << 32) | (unsigned)m;
            if (key <= tau) {
                int pos = atomicAdd(&cnt[lq], 1);
                if (pos < KCAP) buf[lq][pos] = key;
            }
        }
    }
    __syncthreads();
    int c = min(cnt[lq], KCAP);
    for (int s = sub; s < c; s += 32) {
        u64 k = buf[lq][s];
        int r = 0;
        for (int j = 0; j < c; ++j) r += (buf[lq][j] < k);
        if (r < 16) idx[(b * 2048 + q) * 16 + r] = (int)(unsigned)(k & 0xffffffffull);
    }
}

// ---------------------------------------------------------------- precompute (unchanged)
__global__ __launch_bounds__(256) void precompute_kernel(
    const float* __restrict__ Win, const float* __restrict__ Wdin,
    const float* __restrict__ Ws, const float* __restrict__ Wds,
    const float* __restrict__ Gs, const float* __restrict__ Gds,
    const float* __restrict__ Wout,
    us* __restrict__ W1h, us* __restrict__ W1l,
    us* __restrict__ W2h, us* __restrict__ W2l,
    float* __restrict__ Wg, us* __restrict__ Woh, us* __restrict__ Wol,
    float* __restrict__ Mbuf, float* __restrict__ Gbuf) {
    __shared__ float row[128];
    int blk = blockIdx.x, t = threadIdx.x;
    if (blk < 512) {
        int l = blk >> 7, i = blk & 127;
        if (t < 128) row[t] = Wds[l * 16384 + i * 128 + t];
        __syncthreads();
        if (t < 128) {
            float acc = 0.f;
            for (int m = 0; m < 128; ++m) acc += row[m] * Ws[l * 16384 + m * 128 + t];
            wsplit(acc, W1h, W1l, (size_t)l * 32768 + (128 + i) * 128 + t);
            wsplit(Ws[l * 16384 + i * 128 + t], W1h, W1l, (size_t)l * 32768 + i * 128 + t);
        }
    } else if (blk < 1024) {
        int l = (blk - 512) >> 7, i = (blk - 512) & 127;
        if (t < 128) row[t] = Gds[l * 16384 + i * 128 + t];
        __syncthreads();
        float acc = 0.f;
        for (int m = 0; m < 128; ++m) acc += row[m] * Gs[l * 32768 + m * 256 + t];
        if (t < 128) {
            wsplit(acc, W2h, W2l, (size_t)l * 32768 + (128 + i) * 128 + t);
            wsplit(Gs[l * 32768 + i * 256 + t], W2h, W2l, (size_t)l * 32768 + i * 128 + t);
        } else {
            Wg[l * 32768 + (128 + i) * 128 + (t - 128)] = acc;
            Wg[l * 32768 + i * 128 + (t - 128)] = Gs[l * 32768 + i * 256 + t];
        }
    } else if (blk == 1024) {
        if (t < 128) {
            float a0 = 0.f, a1 = 0.f, a2 = 0.f;
            for (int m = 0; m < 128; ++m) {
                float w = Wdin[t * 128 + m];
                a0 += w * Win[m * 3];
                a1 += w * Win[m * 3 + 1];
                a2 += w * Win[m * 3 + 2];
            }
            Mbuf[t * 3] = a0; Mbuf[t * 3 + 1] = a1; Mbuf[t * 3 + 2] = a2;
        } else if (t < 137) {
            int qq = t - 128, a = qq / 3, bb = qq - 3 * a;
            float acc = 0.f;
            for (int m = 0; m < 128; ++m) acc += Win[m * 3 + a] * Win[m * 3 + bb];
            Gbuf[qq] = acc;
        }
    } else {
        int l = blk - 1025;
        for (int i = t; i < 16384; i += 256) {
            int r = i >> 7, j = i & 127;
            wsplit(Wout[r * 512 + l * 128 + j], Woh, Wol, (size_t)l * 16384 + r * 128 + j);
        }
    }
}

// ---------------------------------------------------------------- stage 1
__global__ __launch_bounds__(256) void stage1_kernel(
    const float* __restrict__ x, const int* __restrict__ idx,
    const float* __restrict__ Win, const float* __restrict__ Mbuf,
    const float* __restrict__ Gbuf, us* __restrict__ hhi, us* __restrict__ hlo) {
    __shared__ float Yb[2][16][10];
    __shared__ float Pb[2][16][6];
    __shared__ float SYb[2][9];
    int t = threadIdx.x;
    int blk = blockIdx.x;
    int b = blk >> 10, n0 = (blk & 1023) * 2;
    if (t < 32) {
        int pt = t >> 4, k = t & 15;
        int n = n0 + pt, gpt = b * 2048 + n;
        float pxv = x[b * 6144 + n], pyv = x[b * 6144 + 2048 + n], pzv = x[b * 6144 + 4096 + n];
        float pn = sqrtf(pxv * pxv + pyv * pyv + pzv * pzv);
        float inv = 1.f / fmaxf(pn, EPSV);
        float dx = pxv * inv, dy = pyv * inv, dz = pzv * inv;
        int m = idx[gpt * 16 + k];
        float qx = x[b * 6144 + m], qy = x[b * 6144 + 2048 + m], qz = x[b * 6144 + 4096 + m];
        float Y[9];
        Y[0] = dy * qz - dz * qy; Y[1] = dz * qx - dx * qz; Y[2] = dx * qy - dy * qx;
        Y[3] = qx - pxv; Y[4] = qy - pyv; Y[5] = qz - pzv;
        Y[6] = pxv; Y[7] = pyv; Y[8] = pzv;
        float P[6];
        P[0] = Y[0] * Y[0] + Y[1] * Y[1] + Y[2] * Y[2];
        P[1] = Y[0] * Y[3] + Y[1] * Y[4] + Y[2] * Y[5];
        P[2] = Y[0] * Y[6] + Y[1] * Y[7] + Y[2] * Y[8];
        P[3] = Y[3] * Y[3] + Y[4] * Y[4] + Y[5] * Y[5];
        P[4] = Y[3] * Y[6] + Y[4] * Y[7] + Y[5] * Y[8];
        P[5] = Y[6] * Y[6] + Y[7] * Y[7] + Y[8] * Y[8];
        float nv2 = Gbuf[0] * P[0] + Gbuf[4] * P[3] + Gbuf[8] * P[5] +
                    (Gbuf[1] + Gbuf[3]) * P[1] + (Gbuf[2] + Gbuf[6]) * P[2] +
                    (Gbuf[5] + Gbuf[7]) * P[4];
        float s = 1.f / fmaxf(sqrtf(nv2), EPSV);
#pragma unroll
        for (int j = 0; j < 9; ++j) Yb[pt][k][j] = Y[j];
        Yb[pt][k][9] = s;
#pragma unroll
        for (int j = 0; j < 6; ++j) Pb[pt][k][j] = P[j];
    }
    __syncthreads();
    if (t < 18) {
        int pt = t / 9, j = t - 9 * pt;
        float acc = 0.f;
#pragma unroll
        for (int k = 0; k < 16; ++k) acc += Yb[pt][k][j] * Yb[pt][k][9];
        SYb[pt][j] = acc;
    }
    __syncthreads();
    int pt = t >> 7, h = t & 127;
    int n = n0 + pt;
    float w0 = Win[h * 3], w1 = Win[h * 3 + 1], w2 = Win[h * 3 + 2];
    float m0 = Mbuf[h * 3], m1 = Mbuf[h * 3 + 1], m2 = Mbuf[h * 3 + 2];
    float cA0 = w0 * m0, cA3 = w1 * m1, cA5 = w2 * m2;
    float cA1 = w0 * m1 + w1 * m0, cA2 = w0 * m2 + w2 * m0, cA4 = w1 * m2 + w2 * m1;
    float cR0 = m0 * m0, cR3 = m1 * m1, cR5 = m2 * m2;
    float cR1 = 2.f * m0 * m1, cR2 = 2.f * m0 * m2, cR4 = 2.f * m1 * m2;
    float wY[9] = {0.f, 0.f, 0.f, 0.f, 0.f, 0.f, 0.f, 0.f, 0.f};
    for (int k = 0; k < 16; ++k) {
        const float* Y = Yb[pt][k];
        const float* P = Pb[pt][k];
        float s = Y[9];
        float a = cA0 * P[0] + cA1 * P[1] + cA2 * P[2] + cA3 * P[3] + cA4 * P[4] + cA5 * P[5];
        float r2 = cR0 * P[0] + cR1 * P[1] + cR2 * P[2] + cR3 * P[3] + cR4 * P[4] + cR5 * P[5];
        float an = fminf(a, 0.f);
        float wc = -an * s * __builtin_amdgcn_rcpf(fmaxf(r2, 1e-30f));
#pragma unroll
        for (int j = 0; j < 9; ++j) wY[j] += wc * Y[j];
    }
#pragma unroll
    for (int c = 0; c < 3; ++c) {
        float base = w0 * SYb[pt][c] + w1 * SYb[pt][3 + c] + w2 * SYb[pt][6 + c];
        float corr = m0 * wY[c] + m1 * wY[3 + c] + m2 * wY[6 + c];
        wsplit((base + corr) * (1.f / 16.f), hhi, hlo,
               (size_t)(b * 2048 + n) * 384 + c * 128 + h);
    }
}

// ---------------------------------------------------------------- GEMM helpers
__device__ __forceinline__ void gemm16(
    const us* __restrict__ wvh, const us* __restrict__ wvl,
    const us* __restrict__ wkh, const us* __restrict__ wkl,
    const us* __restrict__ sh, const us* __restrict__ sl,
    int r15, int quad, f32x4 (&av)[3], f32x4 (&ak)[3]) {
#pragma unroll
    for (int j = 0; j < 3; ++j) { av[j] = (f32x4){0.f, 0.f, 0.f, 0.f}; ak[j] = av[j]; }
#pragma unroll
    for (int kc4 = 0; kc4 < 4; ++kc4) {
        int ko = kc4 * 32 + quad * 8;
        short8 avh = *(const short8*)(wvh + ko);
        short8 avl = *(const short8*)(wvl + ko);
        short8 akh = *(const short8*)(wkh + ko);
        short8 akl = *(const short8*)(wkl + ko);
        const us* bp = sh + r15 * PSTR + ko;
        const us* blp = sl + r15 * PSTR + ko;
        short8 bh0 = *(const short8*)(bp);
        short8 bh1 = *(const short8*)(bp + 128);
        short8 bh2 = *(const short8*)(bp + 256);
        short8 bl0 = *(const short8*)(blp);
        short8 bl1 = *(const short8*)(blp + 128);
        short8 bl2 = *(const short8*)(blp + 256);
        mfma3(av[0], avh, avl, bh0, bl0);
        mfma3(av[1], avh, avl, bh1, bl1);
        mfma3(av[2], avh, avl, bh2, bl2);
        mfma3(ak[0], akh, akl, bh0, bl0);
        mfma3(ak[1], akh, akl, bh1, bl1);
        mfma3(ak[2], akh, akl, bh2, bl2);
    }
}

__device__ __forceinline__ void wout16(
    const us* __restrict__ woh, const us* __restrict__ wol,
    const us* __restrict__ sh, const us* __restrict__ sl,
    int r15, int quad, f32x4 (&wa)[3]) {
#pragma unroll
    for (int kc4 = 0; kc4 < 4; ++kc4) {
        int ko = kc4 * 32 + quad * 8;
        short8 ah = *(const short8*)(woh + ko);
        short8 al = *(const short8*)(wol + ko);
#pragma unroll
        for (int nt = 0; nt < 3; ++nt) {
            short8 bh = *(const short8*)(sh + r15 * PSTR + nt * 128 + ko);
            short8 bl = *(const short8*)(sl + r15 * PSTR + nt * 128 + ko);
            mfma3(wa[nt], ah, al, bh, bl);
        }
    }
}

// VN activation epilogue, rcp form (no sqrt/div)
__device__ __forceinline__ void vnact(float s, float vx, float vy, float vz,
                                      float kx, float ky, float kz,
                                      float& o0, float& o1, float& o2) {
    float kk = kx * kx + ky * ky + kz * kz;
    float tt = vx * kx + vy * ky + vz * kz;
    float f = fmaxf(-tt, 0.f) * s * __builtin_amdgcn_rcpf(fmaxf(kk, 1e-30f));
    o0 = s * vx + f * kx;
    o1 = s * vy + f * ky;
    o2 = s * vz + f * kz;
}

// single-barrier reduce (bit-identical to old t<16 path)
__device__ __forceinline__ float rsum8(const float (*colsum)[16], int r15) {
    float c = 0.f;
#pragma unroll
    for (int w = 0; w < 8; ++w) c += colsum[w][r15];
    return 1.f / fmaxf(sqrtf(c), EPSV);
}

// ---------------------------------------------------------------- layer A0
__global__ __launch_bounds__(512, 6) void layerA0_kernel(
    const us* __restrict__ Xhi, const us* __restrict__ Xlo,
    const us* __restrict__ Whi, const us* __restrict__ Wlo,
    us* __restrict__ Hhi, us* __restrict__ Hlo, float* __restrict__ g) {
    __shared__ __align__(16) us stash[2 * HALF];
    __shared__ float colsum[8][16];
    __shared__ float gsh[384];
    us* sh = stash;
    us* sl = stash + HALF;
    int t = threadIdx.x, blk = blockIdx.x;
    int b = blk >> 7, n0 = (blk & 127) * 16;
    size_t pbase = (size_t)(b * 2048 + n0);
    int lane = t & 63, wv = t >> 6;
    int r15 = lane & 15, quad = lane >> 4;
    int rowb = 16 * wv + quad * 4;

    for (int i = t; i < 768; i += 512) {
        int p = i / 48, rem = i - p * 48;
        int c = rem >> 4, k0 = (rem & 15) << 3;
        int lo_ = p * PSTR + c * 128 + k0;
        size_t go = (pbase + p) * 384 + c * 128 + k0;
        *(uint4*)(sh + lo_) = *(const uint4*)(Xhi + go);
        *(uint4*)(sl + lo_) = *(const uint4*)(Xlo + go);
    }
    __syncthreads();

    f32x4 av[3], ak[3];
    gemm16(Whi + (16 * wv + r15) * 128, Wlo + (16 * wv + r15) * 128,
           Whi + (128 + 16 * wv + r15) * 128, Wlo + (128 + 16 * wv + r15) * 128,
           sh, sl, r15, quad, av, ak);

    float S = 0.f;
#pragma unroll
    for (int nt = 0; nt < 3; ++nt)
#pragma unroll
        for (int reg = 0; reg < 4; ++reg) S += av[nt][reg] * av[nt][reg];
    S += __shfl_xor(S, 16, 64);
    S += __shfl_xor(S, 32, 64);
    if (quad == 0) colsum[wv][r15] = S;
    __syncthreads();
    float s = rsum8(colsum, r15);
#pragma unroll
    for (int reg = 0; reg < 4; ++reg) {
        int row = rowb + reg;
        float o0, o1, o2;
        vnact(s, av[0][reg], av[1][reg], av[2][reg],
              ak[0][reg], ak[1][reg], ak[2][reg], o0, o1, o2);
        int sb = r15 * PSTR + row;
        us h0 = f2bf(o0); sh[sb] = h0;           sl[sb] = f2bf(o0 - bf2f(h0));
        us h1 = f2bf(o1); sh[sb + 128] = h1;     sl[sb + 128] = f2bf(o1 - bf2f(h1));
        us h2 = f2bf(o2); sh[sb + 256] = h2;     sl[sb + 256] = f2bf(o2 - bf2f(h2));
        float g0 = o0, g1 = o1, g2 = o2;
#pragma unroll
        for (int m = 1; m < 16; m <<= 1) {
            g0 += __shfl_xor(g0, m, 64);
            g1 += __shfl_xor(g1, m, 64);
            g2 += __shfl_xor(g2, m, 64);
        }
        if (r15 == 0) {
            gsh[row] = g0;
            gsh[128 + row] = g1;
            gsh[256 + row] = g2;
        }
    }
    __syncthreads();
    for (int i = t; i < 768; i += 512) {
        int p = i / 48, rem = i - p * 48;
        int c = rem >> 4, k0 = (rem & 15) << 3;
        int lo_ = p * PSTR + c * 128 + k0;
        size_t go = (pbase + p) * 384 + c * 128 + k0;
        *(uint4*)(Hhi + go) = *(const uint4*)(sh + lo_);
        *(uint4*)(Hlo + go) = *(const uint4*)(sl + lo_);
    }
    if (t < 384) atomicAdd(&g[b * 384 + t], gsh[t]);
}

// ---------------------------------------------------------------- layer BA
template <int FIRST>
__global__ __launch_bounds__(512, 4) void layerBA_kernel(
    const us* __restrict__ Xhi, const us* __restrict__ Xlo,
    const float* __restrict__ gin, const float* __restrict__ Wgl,
    const us* __restrict__ W2h, const us* __restrict__ W2l,
    const us* __restrict__ Woh, const us* __restrict__ Wol,
    const us* __restrict__ W1h, const us* __restrict__ W1l,
    us* __restrict__ Hhi, us* __restrict__ Hlo, float* __restrict__ gout,
    float* __restrict__ accb) {
    __shared__ __align__(16) us stash[2 * HALF];
    __shared__ float gl[384];
    __shared__ float biasl[768];
    __shared__ float colsum[8][16];
    __shared__ float gsh[384];
    us* sh = stash;
    us* sl = stash + HALF;
    int t = threadIdx.x, blk = blockIdx.x;
    int b = blk >> 7, n0 = (blk & 127) * 16;
    size_t pbase = (size_t)(b * 2048 + n0);
    int lane = t & 63, wv = t >> 6;
    int r15 = lane & 15, quad = lane >> 4;
    int rowb = 16 * wv + quad * 4;

    for (int i = t; i < 768; i += 512) {
        int p = i / 48, rem = i - p * 48;
        int c = rem >> 4, k0 = (rem & 15) << 3;
        int lo_ = p * PSTR + c * 128 + k0;
        size_t go = (pbase + p) * 384 + c * 128 + k0;
        *(uint4*)(sh + lo_) = *(const uint4*)(Xhi + go);
        *(uint4*)(sl + lo_) = *(const uint4*)(Xlo + go);
    }
    if (t < 384) gl[t] = gin[b * 384 + t] * (1.f / 2048.f);
    __syncthreads();

    f32x4 av[3], ak[3];
    gemm16(W2h + (16 * wv + r15) * 128, W2l + (16 * wv + r15) * 128,
           W2h + (128 + 16 * wv + r15) * 128, W2l + (128 + 16 * wv + r15) * 128,
           sh, sl, r15, quad, av, ak);
    if (t < 256) {
        float accv[3] = {0.f, 0.f, 0.f};
        const float4* wr = (const float4*)&Wgl[t * 128];
        for (int jj = 0; jj < 32; ++jj) {
            float4 w4 = wr[jj];
#pragma unroll
            for (int c = 0; c < 3; ++c) {
                float4 gq = *(const float4*)&gl[c * 128 + 4 * jj];
                accv[c] += w4.x * gq.x + w4.y * gq.y + w4.z * gq.z + w4.w * gq.w;
            }
        }
#pragma unroll
        for (int c = 0; c < 3; ++c) biasl[c * 256 + t] = accv[c];
    }
    __syncthreads();

    float S = 0.f;
#pragma unroll
    for (int reg = 0; reg < 4; ++reg) {
        int row = rowb + reg;
#pragma unroll
        for (int c = 0; c < 3; ++c) {
            float v = av[c][reg] + biasl[c * 256 + row];
            S += v * v;
        }
    }
    S += __shfl_xor(S, 16, 64);
    S += __shfl_xor(S, 32, 64);
    if (quad == 0) colsum[wv][r15] = S;
    __syncthreads();
    float s = rsum8(colsum, r15);
#pragma unroll
    for (int reg = 0; reg < 4; ++reg) {
        int row = rowb + reg;
        float o0, o1, o2;
        vnact(s, av[0][reg] + biasl[row], av[1][reg] + biasl[256 + row],
              av[2][reg] + biasl[512 + row],
              ak[0][reg] + biasl[128 + row], ak[1][reg] + biasl[384 + row],
              ak[2][reg] + biasl[640 + row], o0, o1, o2);
        int sb = r15 * PSTR + row;
        us h0 = f2bf(o0); sh[sb] = h0;           sl[sb] = f2bf(o0 - bf2f(h0));
        us h1 = f2bf(o1); sh[sb + 128] = h1;     sl[sb + 128] = f2bf(o1 - bf2f(h1));
        us h2 = f2bf(o2); sh[sb + 256] = h2;     sl[sb + 256] = f2bf(o2 - bf2f(h2));
    }
    __syncthreads();

    f32x4 wa[3];
#pragma unroll
    for (int j = 0; j < 3; ++j) wa[j] = (f32x4){0.f, 0.f, 0.f, 0.f};
    wout16(Woh + (16 * wv + r15) * 128, Wol + (16 * wv + r15) * 128,
           sh, sl, r15, quad, wa);
    f32x4 av2[3], ak2[3];
    gemm16(W1h + (16 * wv + r15) * 128, W1l + (16 * wv + r15) * 128,
           W1h + (128 + 16 * wv + r15) * 128, W1l + (128 + 16 * wv + r15) * 128,
           sh, sl, r15, quad, av2, ak2);

    float S2 = 0.f;
#pragma unroll
    for (int nt = 0; nt < 3; ++nt)
#pragma unroll
        for (int reg = 0; reg < 4; ++reg) S2 += av2[nt][reg] * av2[nt][reg];
    S2 += __shfl_xor(S2, 16, 64);
    S2 += __shfl_xor(S2, 32, 64);
    if (quad == 0) colsum[wv][r15] = S2;
    __syncthreads();
    float s2 = rsum8(colsum, r15);
#pragma unroll
    for (int reg = 0; reg < 4; ++reg) {
        int row = rowb + reg;
        float o0, o1, o2;
        vnact(s2, av2[0][reg], av2[1][reg], av2[2][reg],
              ak2[0][reg], ak2[1][reg], ak2[2][reg], o0, o1, o2);
        int sb = r15 * PSTR + row;
        us h0 = f2bf(o0); sh[sb] = h0;           sl[sb] = f2bf(o0 - bf2f(h0));
        us h1 = f2bf(o1); sh[sb + 128] = h1;     sl[sb + 128] = f2bf(o1 - bf2f(h1));
        us h2 = f2bf(o2); sh[sb + 256] = h2;     sl[sb + 256] = f2bf(o2 - bf2f(h2));
        float g0 = o0, g1 = o1, g2 = o2;
#pragma unroll
        for (int m = 1; m < 16; m <<= 1) {
            g0 += __shfl_xor(g0, m, 64);
            g1 += __shfl_xor(g1, m, 64);
            g2 += __shfl_xor(g2, m, 64);
        }
        if (r15 == 0) {
            gsh[row] = g0;
            gsh[128 + row] = g1;
            gsh[256 + row] = g2;
        }
    }
    __syncthreads();
    for (int i = t; i < 768; i += 512) {
        int p = i / 48, rem = i - p * 48;
        int c = rem >> 4, k0 = (rem & 15) << 3;
        int lo_ = p * PSTR + c * 128 + k0;
        size_t go = (pbase + p) * 384 + c * 128 + k0;
        *(uint4*)(Hhi + go) = *(const uint4*)(sh + lo_);
        *(uint4*)(Hlo + go) = *(const uint4*)(sl + lo_);
    }
    __syncthreads();
    float* accf = (float*)stash;
#pragma unroll
    for (int nt = 0; nt < 3; ++nt)
#pragma unroll
        for (int reg = 0; reg < 4; ++reg)
            accf[r15 * PSTR + nt * 128 + rowb + reg] = wa[nt][reg];
    __syncthreads();
    // tight RMW at tail: acc lines L3-hot from prev dispatch (R14/R19 lesson)
    for (int i = t; i < 1536; i += 512) {
        int p = i / 96, rem = i - p * 96;
        int c = rem >> 5, k4 = (rem & 31) << 2;
        float4 vv = *(const float4*)&accf[p * PSTR + c * 128 + k4];
        size_t go = (pbase + p) * 384 + c * 128 + k4;
        if (FIRST) {
            *(float4*)&accb[go] = vv;
        } else {
            float4 old = *(const float4*)&accb[go];
            old.x += vv.x; old.y += vv.y; old.z += vv.z; old.w += vv.w;
            *(float4*)&accb[go] = old;
        }
    }
    if (t < 384) atomicAdd(&gout[b * 384 + t], gsh[t]);
}

// ---------------------------------------------------------------- layer B3 + out
__global__ __launch_bounds__(512, 6) void layerB3_kernel(
    const us* __restrict__ Xhi, const us* __restrict__ Xlo,
    const float* __restrict__ gin, const float* __restrict__ Wgl,
    const us* __restrict__ W2h, const us* __restrict__ W2l,
    const us* __restrict__ Woh, const us* __restrict__ Wol,
    const float* __restrict__ accb,
    float* __restrict__ out1, float* __restrict__ out0) {
    __shared__ __align__(16) us stash[2 * HALF];
    __shared__ float gl[384];
    __shared__ float biasl[768];
    __shared__ float colsum[8][16];
    us* sh = stash;
    us* sl = stash + HALF;
    int t = threadIdx.x, blk = blockIdx.x;
    int b = blk >> 7, n0 = (blk & 127) * 16;
    size_t pbase = (size_t)(b * 2048 + n0);
    int lane = t & 63, wv = t >> 6;
    int r15 = lane & 15, quad = lane >> 4;
    int rowb = 16 * wv + quad * 4;

    for (int i = t; i < 768; i += 512) {
        int p = i / 48, rem = i - p * 48;
        int c = rem >> 4, k0 = (rem & 15) << 3;
        int lo_ = p * PSTR + c * 128 + k0;
        size_t go = (pbase + p) * 384 + c * 128 + k0;
        *(uint4*)(sh + lo_) = *(const uint4*)(Xhi + go);
        *(uint4*)(sl + lo_) = *(const uint4*)(Xlo + go);
    }
    if (t < 384) gl[t] = gin[b * 384 + t] * (1.f / 2048.f);
    __syncthreads();

    f32x4 av[3], ak[3];
    gemm16(W2h + (16 * wv + r15) * 128, W2l + (16 * wv + r15) * 128,
           W2h + (128 + 16 * wv + r15) * 128, W2l + (128 + 16 * wv + r15) * 128,
           sh, sl, r15, quad, av, ak);
    if (t < 256) {
        float accv[3] = {0.f, 0.f, 0.f};
        const float4* wr = (const float4*)&Wgl[t * 128];
        for (int jj = 0; jj < 32; ++jj) {
            float4 w4 = wr[jj];
#pragma unroll
            for (int c = 0; c < 3; ++c) {
                float4 gq = *(const float4*)&gl[c * 128 + 4 * jj];
                accv[c] += w4.x * gq.x + w4.y * gq.y + w4.z * gq.z + w4.w * gq.w;
            }
        }
#pragma unroll
        for (int c = 0; c < 3; ++c) biasl[c * 256 + t] = accv[c];
    }
    __syncthreads();

    float S = 0.f;
#pragma unroll
    for (int reg = 0; reg < 4; ++reg) {
        int row = rowb + reg;
#pragma unroll
        for (int c = 0; c < 3; ++c) {
            float v = av[c][reg] + biasl[c * 256 + row];
            S += v * v;
        }
    }
    S += __shfl_xor(S, 16, 64);
    S += __shfl_xor(S, 32, 64);
    if (quad == 0) colsum[wv][r15] = S;
    __syncthreads();
    float s = rsum8(colsum, r15);
#pragma unroll
    for (int reg = 0; reg < 4; ++reg) {
        int row = rowb + reg;
        float o0, o1, o2;
        vnact(s, av[0][reg] + biasl[row], av[1][reg] + biasl[256 + row],
              av[2][reg] + biasl[512 + row],
              ak[0][reg] + biasl[128 + row], ak[1][reg] + biasl[384 + row],
              ak[2][reg] + biasl[640 + row], o0, o1, o2);
        int sb = r15 * PSTR + row;
        us h0 = f2bf(o0); sh[sb] = h0;           sl[sb] = f2bf(o0 - bf2f(h0));
        us h1 = f2bf(o1); sh[sb + 128] = h1;     sl[sb + 128] = f2bf(o1 - bf2f(h1));
        us h2 = f2bf(o2); sh[sb + 256] = h2;     sl[sb + 256] = f2bf(o2 - bf2f(h2));
    }
    __syncthreads();

    f32x4 wa[3];
#pragma unroll
    for (int j = 0; j < 3; ++j) wa[j] = (f32x4){0.f, 0.f, 0.f, 0.f};
    wout16(Woh + (16 * wv + r15) * 128, Wol + (16 * wv + r15) * 128,
           sh, sl, r15, quad, wa);
    __syncthreads();
    float* accf = (float*)stash;
#pragma unroll
    for (int nt = 0; nt < 3; ++nt)
#pragma unroll
        for (int reg = 0; reg < 4; ++reg)
            accf[r15 * PSTR + nt * 128 + rowb + reg] = wa[nt][reg];
    __syncthreads();
    for (int i = t; i < 1536; i += 512) {
        int p = i / 96, rem = i - p * 96;
        int c = rem >> 5, k4 = (rem & 31) << 2;
        size_t go = (pbase + p) * 384 + c * 128 + k4;
        float4 old = *(const float4*)&accb[go];
        float4* pl = (float4*)&accf[p * PSTR + c * 128 + k4];
        float4 vv = *pl;
        vv.x += old.x; vv.y += old.y; vv.z += old.z; vv.w += old.w;
        *pl = vv;
    }
    __syncthreads();
    for (int i = t; i < 6144; i += 512) {
        int j = i >> 4, nl = i & 15;
        float v = accf[nl * PSTR + j];
        out1[((size_t)b * 384 + (j & 127) * 3 + (j >> 7)) * 2048 + n0 + nl] = v;
    }
    if (t < 384) {
        float ssum = 0.f;
#pragma unroll
        for (int nl = 0; nl < 16; ++nl) ssum += accf[nl * PSTR + t];
        atomicAdd(&out0[b * 384 + (t & 127) * 3 + (t >> 7)], ssum * (1.f / 2048.f));
    }
}

// ---------------------------------------------------------------- launch
extern "C" void kernel_launch(void* const* d_in, const int* in_sizes, int n_in,
                              void* d_out, int out_size, void* d_ws, size_t ws_size,
                              hipStream_t stream) {
    const float* x    = (const float*)d_in[0];
    const float* Win  = (const float*)d_in[1];
    const float* Wdin = (const float*)d_in[2];
    const float* Ws   = (const float*)d_in[3];
    const float* Wds  = (const float*)d_in[4];
    const float* Gs   = (const float*)d_in[5];
    const float* Gds  = (const float*)d_in[6];
    const float* Wout = (const float*)d_in[7];

    float* out0 = (float*)d_out;   // (B,CD,3) = 3072
    float* out1 = out0 + 3072;     // (B,CD,3,N)

    char* ws = (char*)d_ws;
    int* idx = (int*)ws;                            // 1 MB
    us* hAhi = (us*)(ws + (1 << 20));               // 6291456 bf16 each
    us* hAlo = hAhi + 6291456;
    us* hBhi = hAlo + 6291456;
    us* hBlo = hBhi + 6291456;
    float* acc = (float*)(hBlo + 6291456);          // 6291456 f32
    float* g4 = acc + 6291456;                      // 4 x 3072
    us* W1h = (us*)(g4 + 12288);                    // 131072 each
    us* W1l = W1h + 131072;
    us* W2h = W1l + 131072;
    us* W2l = W2h + 131072;
    us* Woh = W2l + 131072;                         // 65536 each
    us* Wol = Woh + 65536;
    float* Wg = (float*)(Wol + 65536);              // 131072 f32
    float* Mbuf = Wg + 131072;                      // 384
    float* Gbuf = Mbuf + 384;                       // 16

    hipMemsetAsync(out0, 0, (size_t)3072 * 4, stream);
    hipMemsetAsync(g4, 0, (size_t)12288 * 4, stream);

    knn_kernel<<<dim3(256, 8), 256, 0, stream>>>(x, idx);
    precompute_kernel<<<1029, 256, 0, stream>>>(Win, Wdin, Ws, Wds, Gs, Gds, Wout,
                                                W1h, W1l, W2h, W2l, Wg, Woh, Wol,
                                                Mbuf, Gbuf);
    stage1_kernel<<<8192, 256, 0, stream>>>(x, idx, Win, Mbuf, Gbuf, hAhi, hAlo);

    // A(0): hA -> hB, g4[0]
    layerA0_kernel<<<1024, 512, 0, stream>>>(hAhi, hAlo, W1h, W1l, hBhi, hBlo, g4);
    // B(0)+wout(0)+A(1): hB -> hA, g4[1], acc (first write)
    layerBA_kernel<1><<<1024, 512, 0, stream>>>(
        hBhi, hBlo, g4, Wg, W2h, W2l, Woh, Wol,
        W1h + 32768, W1l + 32768, hAhi, hAlo, g4 + 3072, acc);
    // B(1)+wout(1)+A(2): hA -> hB, g4[2], acc +=
    layerBA_kernel<0><<<1024, 512, 0, stream>>>(
        hAhi, hAlo, g4 + 3072, Wg + 32768, W2h + 32768, W2l + 32768,
        Woh + 16384, Wol + 16384, W1h + 65536, W1l + 65536,
        hBhi, hBlo, g4 + 6144, acc);
    // B(2)+wout(2)+A(3): hB -> hA, g4[3], acc +=
    layerBA_kernel<0><<<1024, 512, 0, stream>>>(
        hBhi, hBlo, g4 + 6144, Wg + 65536, W2h + 65536, W2l + 65536,
        Woh + 32768, Wol + 32768, W1h + 98304, W1l + 98304,
        hAhi, hAlo, g4 + 9216, acc);
    // B(3)+wout(3) + acc readback -> out1/out0
    layerB3_kernel<<<1024, 512, 0, stream>>>(
        hAhi, hAlo, g4 + 9216, Wg + 98304, W2h + 98304, W2l + 98304,
        Woh + 49152, Wol + 49152, acc, out1, out0);
}